// Round 10
// baseline (81.615 us; speedup 1.0000x reference)
//
#include <hip/hip_runtime.h>
#include <math.h>
#include <utility>

#define NPTS 262144
#define K 32
#define D 16
#define R 160            // 136 triangle + 16 linear + 8 pad -> 10 MFMA K-steps
#define NSTEPS 10
#define NBLK 2048        // 4 waves/block, 1 tile/wave -> 8192 tiles
#define LROW 352         // 20 data granules (320 B) + 2 pad granules per row
#define LHALF 11264      // 32 rows * 352 B ; thetaL LDS region offset
#define REPS 4           // INSTRUMENTATION: rep-loop so density enters top-5.

typedef __attribute__((ext_vector_type(8))) short bf16x8;
typedef __attribute__((ext_vector_type(16))) float f32x16;
typedef __attribute__((ext_vector_type(4))) int int4v;

// ---- compile-time slot table (round-8 pairing, kh-uniform u factor) ----
struct PTab {
  short pd[160], pf[160];               // per slot (prep kernel)
  short u0[80], v0[80], u1[80], v1[80]; // per cell (density kernel)
  constexpr PTab() : pd{}, pf{}, u0{}, v0{}, u1{}, v1{} {
    int nc = 0;
    for (int d = 0; d < 16; ++d) {
      int f = d;
      while (f + 1 <= 15) {
        u0[nc] = (short)d; v0[nc] = (short)f;
        u1[nc] = (short)d; v1[nc] = (short)(f + 1);
        ++nc; f += 2;
      }
    }
    for (int i = 0; i < 4; ++i) {
      u0[nc] = (short)(4*i+1); v0[nc] = 15;
      u1[nc] = (short)(4*i+3); v1[nc] = 15; ++nc;
    }
    for (int i = 0; i < 8; ++i) {
      u0[nc] = 16; v0[nc] = (short)(2*i);
      u1[nc] = 16; v1[nc] = (short)(2*i+1); ++nc;
    }
    for (int i = 0; i < 4; ++i) {
      u0[nc] = 17; v0[nc] = 17; u1[nc] = 17; v1[nc] = 17; ++nc;
    }
    for (int c = 0; c < 80; ++c) {
      int S = c / 8, j = c % 8;
      pd[S*16 + j]     = u0[c]; pf[S*16 + j]     = v0[c];
      pd[S*16 + 8 + j] = u1[c]; pf[S*16 + 8 + j] = v1[c];
    }
  }
};
static constexpr PTab TAB{};

// ---------------- prep kernel (unchanged from round 9) ----------------
__global__ __launch_bounds__(256) void gm_prep_kernel(
    const float* __restrict__ m_w,
    const float* __restrict__ l_fac,
    const float* __restrict__ p_logits,
    unsigned short* __restrict__ thetaH,
    unsigned short* __restrict__ thetaL,
    float* __restrict__ lc_out)
{
  const int k = blockIdx.x;
  const int tid = threadIdx.x;
  const int r = tid >> 4, c = tid & 15;
  __shared__ float A[D][D];
  __shared__ float L[D][D];
  __shared__ float S[2][D][D];
  __shared__ float Gd[D];
  __shared__ float ld[D];
  __shared__ float sm[K];
  const float LOG2E = 1.4426950408889634f;

  A[r][c] = l_fac[k * D * D + r * D + c];
  if (tid < K) sm[tid] = p_logits[tid];
  __syncthreads();

  {
    float s = 0.f;
    #pragma unroll
    for (int e = 0; e < D; ++e) s += A[r][e] * A[c][e];
    s *= (1.0f / D);
    L[r][c] = s;
    S[0][r][c] = s;
  }
  __syncthreads();

  if (tid < D) {
    float s = 0.f;
    #pragma unroll
    for (int f = 0; f < D; ++f) s += L[tid][f] * m_w[k * D + f];
    Gd[tid] = s;
  }

  int cb = 0;
  for (int j = 0; j < 15; ++j) {
    float pj = S[cb][j][j];
    float a = S[cb][r][j], b = S[cb][c][j], v = S[cb][r][c];
    if (tid == 0) ld[j] = logf(pj);
    if (r > j && c > j) S[cb ^ 1][r][c] = v - a * b / pj;
    cb ^= 1;
    __syncthreads();
  }
  if (tid == 0) {
    ld[15] = logf(S[cb][15][15]);
    float mx = -1e30f;
    for (int i = 0; i < K; ++i) mx = fmaxf(mx, sm[i]);
    float z = 0.f;
    for (int i = 0; i < K; ++i) z += expf(sm[i] - mx);
    float logp = sm[k] - mx - logf(z);
    float logdet_sqrt = 0.f;
    for (int j = 0; j < D; ++j) logdet_sqrt += ld[j];
    logdet_sqrt *= 0.5f;
    float cc = 0.f;
    for (int d2 = 0; d2 < D; ++d2) cc += m_w[k * D + d2] * Gd[d2];
    float lc = logp - 14.703016531274763f + logdet_sqrt - 0.5f * cc;
    lc_out[k] = LOG2E * lc;
  }
  __syncthreads();

  for (int q = tid; q < R; q += 256) {
    int d = TAB.pd[q], f = TAB.pf[q];
    float th;
    if (d == 17) th = 0.f;
    else if (d == 16) th = LOG2E * Gd[f];
    else th = ((d == f) ? -0.5f : -1.0f) * LOG2E * L[d][f];
    unsigned u = __float_as_uint(th);
    float hi = __uint_as_float(u & 0xFFFF0000u);
    float lo = th - hi;
    thetaH[k * R + q] = (unsigned short)(u >> 16);
    thetaL[k * R + q] = (unsigned short)(__float_as_uint(lo) >> 16);
  }
}

__device__ __forceinline__ int pack_bf16_hi(unsigned u0, unsigned u1) {
  return (int)__builtin_amdgcn_perm(u1, u0, 0x07060302u);
}

template<int S, int J>
__device__ __forceinline__ float prodSJ(const float (&xs)[16], int kh) {
  constexpr int U0 = TAB.u0[S*8+J], V0 = TAB.v0[S*8+J];
  constexpr int U1 = TAB.u1[S*8+J], V1 = TAB.v1[S*8+J];
  if constexpr (U0 == 17) {
    return 0.0f;
  } else if constexpr (U0 == 16) {
    if constexpr (V0 == V1) return xs[V0];
    else return kh ? xs[V1] : xs[V0];
  } else {
    float u, v;
    if constexpr (U0 == U1) u = xs[U0]; else u = kh ? xs[U1] : xs[U0];
    if constexpr (V0 == V1) v = xs[V0]; else v = kh ? xs[V1] : xs[V0];
    return u * v;
  }
}

template<int S>
__device__ __forceinline__ void build_phi(const float (&xs)[16], int kh,
                                          int4v& ph, int4v& pl) {
  float q[8];
  q[0] = prodSJ<S,0>(xs,kh); q[1] = prodSJ<S,1>(xs,kh);
  q[2] = prodSJ<S,2>(xs,kh); q[3] = prodSJ<S,3>(xs,kh);
  q[4] = prodSJ<S,4>(xs,kh); q[5] = prodSJ<S,5>(xs,kh);
  q[6] = prodSJ<S,6>(xs,kh); q[7] = prodSJ<S,7>(xs,kh);
  #pragma unroll
  for (int a = 0; a < 4; ++a) {
    unsigned u0 = __float_as_uint(q[2*a]), u1 = __float_as_uint(q[2*a+1]);
    ph[a] = pack_bf16_hi(u0, u1);
    float h0 = __uint_as_float(u0 & 0xFFFF0000u);
    float h1 = __uint_as_float(u1 & 0xFFFF0000u);
    pl[a] = pack_bf16_hi(__float_as_uint(q[2*a] - h0),
                         __float_as_uint(q[2*a+1] - h1));
  }
}

// SPLIT=false: all 3 MFMA chain through accA (round-9 behavior, 30-chain).
// SPLIT=true: th*ph->A, tl*ph->B, th*pl alternates by S parity -> 15/15 chains.
template<int S, bool SPLIT>
__device__ __forceinline__ void do_step(const float (&xs)[16], int kh,
    const char* lthp, int base2, int sigh, f32x16& accA, f32x16& accB) {
  int va;
  if constexpr (S < 8) va = base2 + ((S ^ sigh) << 5);
  else                 va = base2 + 256 + (((S - 8) ^ (sigh & 1)) << 5);
  int4v thv = *(const int4v*)(lthp + va);
  int4v tlv = *(const int4v*)(lthp + va + LHALF);
  int4v ph, pl;
  build_phi<S>(xs, kh, ph, pl);
  accA = __builtin_amdgcn_mfma_f32_32x32x16_bf16(
      __builtin_bit_cast(bf16x8, thv), __builtin_bit_cast(bf16x8, ph), accA, 0, 0, 0);
  if constexpr (SPLIT) {
    accB = __builtin_amdgcn_mfma_f32_32x32x16_bf16(
        __builtin_bit_cast(bf16x8, tlv), __builtin_bit_cast(bf16x8, ph), accB, 0, 0, 0);
    if constexpr (S & 1)
      accA = __builtin_amdgcn_mfma_f32_32x32x16_bf16(
          __builtin_bit_cast(bf16x8, thv), __builtin_bit_cast(bf16x8, pl), accA, 0, 0, 0);
    else
      accB = __builtin_amdgcn_mfma_f32_32x32x16_bf16(
          __builtin_bit_cast(bf16x8, thv), __builtin_bit_cast(bf16x8, pl), accB, 0, 0, 0);
  } else {
    accA = __builtin_amdgcn_mfma_f32_32x32x16_bf16(
        __builtin_bit_cast(bf16x8, tlv), __builtin_bit_cast(bf16x8, ph), accA, 0, 0, 0);
    accA = __builtin_amdgcn_mfma_f32_32x32x16_bf16(
        __builtin_bit_cast(bf16x8, thv), __builtin_bit_cast(bf16x8, pl), accA, 0, 0, 0);
  }
}

template<bool SPLIT, int... Ss>
__device__ __forceinline__ void all_steps(std::integer_sequence<int, Ss...>,
    const float (&xs)[16], int kh, const char* lthp, int base2, int sigh,
    f32x16& accA, f32x16& accB) {
  (do_step<Ss, SPLIT>(xs, kh, lthp, base2, sigh, accA, accB), ...);
}

// ---------------- density kernel, REPS-instrumented A/B ----------------
__global__ __launch_bounds__(256) void gm_mfma_kernel_helper();  // (unused decl)

template<bool SPLIT>
__global__ __launch_bounds__(256) void gm_mfma_kernel(
    const float* __restrict__ x,
    const unsigned short* __restrict__ thetaH,
    const unsigned short* __restrict__ thetaL,
    const float* __restrict__ lc,
    float* __restrict__ out)
{
  __shared__ __align__(16) char lth[2 * LHALF];
  const int tid = threadIdx.x;
  const int lane = tid & 63;
  const int p = lane & 31;
  const int kh = lane >> 5;
  const int t = blockIdx.x * 4 + (tid >> 6);

  const float4* xp = (const float4*)(x + ((size_t)t * 32 + p) * D);
  float4 xv0 = xp[0], xv1 = xp[1], xv2 = xp[2], xv3 = xp[3];

  for (int i = tid; i < 1280; i += 256) {
    int half = i >= 640;
    int g = half ? i - 640 : i;
    int row = g / 20;
    int m = g - row * 20;
    int sg = (row & 7) ^ (row >> 3);
    int phys = (m < 16) ? (m ^ sg) : (16 + ((m - 16) ^ (sg & 3)));
    const unsigned short* src = (half ? thetaL : thetaH) + row * R + m * 8;
    int4v v = *(const int4v*)src;
    *(int4v*)(lth + half * LHALF + row * LROW + phys * 16) = v;
  }

  float lcv[16];
  #pragma unroll
  for (int i = 0; i < 16; ++i)
    lcv[i] = lc[(i & 3) + 8 * (i >> 2) + 4 * kh];

  __syncthreads();

  const int sig = (p & 7) ^ (p >> 3);
  const int base2_c = p * LROW + ((kh ^ (sig & 1)) << 4);
  const int sigh = sig >> 1;

  float xs[16];
  xs[0]=xv0.x; xs[1]=xv0.y; xs[2]=xv0.z; xs[3]=xv0.w;
  xs[4]=xv1.x; xs[5]=xv1.y; xs[6]=xv1.z; xs[7]=xv1.w;
  xs[8]=xv2.x; xs[9]=xv2.y; xs[10]=xv2.z; xs[11]=xv2.w;
  xs[12]=xv3.x; xs[13]=xv3.y; xs[14]=xv3.z; xs[15]=xv3.w;

  #pragma unroll 1
  for (int rep = 0; rep < REPS; ++rep) {
    // opaque per rep: block folding/hoisting across reps (rule #17)
    int b2 = base2_c;
    asm volatile("" : "+v"(b2));
    #pragma unroll
    for (int i = 0; i < 16; ++i) asm volatile("" : "+v"(xs[i]));

    f32x16 accA, accB;
    #pragma unroll
    for (int i = 0; i < 16; ++i) accA[i] = 0.f;
    if constexpr (SPLIT) {
      #pragma unroll
      for (int i = 0; i < 16; ++i) accB[i] = 0.f;
    }

    all_steps<SPLIT>(std::make_integer_sequence<int, NSTEPS>{}, xs, kh, lth,
                     b2, sigh, accA, accB);

    float e[16];
    #pragma unroll
    for (int i = 0; i < 16; ++i) {
      float base;
      if constexpr (SPLIT) base = accA[i] + accB[i] + lcv[i];
      else base = accA[i] + lcv[i];
      e[i] = __builtin_amdgcn_exp2f(base);
    }
    float a0 = (e[0] + e[1]) + (e[2] + e[3]);
    float a1 = (e[4] + e[5]) + (e[6] + e[7]);
    float a2 = (e[8] + e[9]) + (e[10] + e[11]);
    float a3 = (e[12] + e[13]) + (e[14] + e[15]);
    float ss = (a0 + a1) + (a2 + a3);
    ss += __shfl_xor(ss, 32);
    if (lane < 32) out[(size_t)t * 32 + p] = ss;
  }
}

extern "C" void kernel_launch(void* const* d_in, const int* in_sizes, int n_in,
                              void* d_out, int out_size, void* d_ws, size_t ws_size,
                              hipStream_t stream) {
  const float* x        = (const float*)d_in[0];
  const float* m_w      = (const float*)d_in[1];
  const float* l_fac    = (const float*)d_in[2];
  const float* p_logits = (const float*)d_in[3];
  float* out = (float*)d_out;

  char* ws = (char*)d_ws;
  unsigned short* thetaH = (unsigned short*)(ws);
  unsigned short* thetaL = (unsigned short*)(ws + K * R * 2);
  float* lc              = (float*)(ws + 2 * K * R * 2);

  gm_prep_kernel<<<K, 256, 0, stream>>>(m_w, l_fac, p_logits, thetaH, thetaL, lc);
  // A/B instrumentation: variant A (single acc chain) then variant B (split
  // chains). B runs last -> final d_out comes from B (correct output).
  gm_mfma_kernel<false><<<NBLK, 256, 0, stream>>>(x, thetaH, thetaL, lc, out);
  gm_mfma_kernel<true ><<<NBLK, 256, 0, stream>>>(x, thetaH, thetaL, lc, out);
}

// Round 12
// 21.569 us; speedup vs baseline: 3.7840x; 3.7840x over previous
//
#include <hip/hip_runtime.h>
#include <math.h>
#include <utility>

#define NPTS 262144
#define K 32
#define D 16
#define R 160            // 136 triangle + 16 linear + 8 pad -> 10 MFMA K-steps
#define NSTEPS 10
#define NBLK 2048        // 4 waves/block, 1 tile/wave -> 8192 tiles
#define LROW 352         // 20 data granules + 2 pad granules per theta row
#define LHALF 11264      // 32 rows * 352 B ; thetaL image offset
#define IMG_BYTES 22528  // 2 * LHALF

typedef _Float16 f16x2 __attribute__((ext_vector_type(2)));
typedef _Float16 f16x8 __attribute__((ext_vector_type(8)));
typedef __attribute__((ext_vector_type(16))) float f32x16;
typedef __attribute__((ext_vector_type(4))) int int4v;

// ---- compile-time dual-cell table --------------------------------------
// 40 duals; dual c = (step S=c/4, dword a=c%4) holds 4 features: 2 for kh=0
// (slots S*16+a*2+{0,1}) and 2 for kh=1 (slots S*16+8+a*2+{0,1}).
// Types: 0=ROW (u-splat x v-pair, v shared between kh), 1=ROWX (even-diag
// leftovers, u and v differ), 2=DIAG (odd diagonals via marshaled pairs),
// 3=LIN (phi = x: register-ready, zero VALU), 4=PAD.
struct PTab {
  short dty[40], cu0[40], cv0[40], cu1[40], cv1[40];
  short pd[160], pf[160];              // per-slot (d,f) for the prep kernel
  constexpr PTab() : dty{}, cu0{}, cv0{}, cu1{}, cv1{}, pd{}, pf{} {
    int n = 0;
    for (int j = 0; j < 8; ++j)                     // 28 ROW duals
      for (int i = 0; i < j; ++i) {
        dty[n]=0; cu0[n]=(short)(2*i); cv0[n]=(short)j;
        cu1[n]=(short)(2*i+1); cv1[n]=(short)j; ++n;
      }
    for (int t = 0; t < 4; ++t) {                   // 4 ROWX duals
      dty[n]=1; cu0[n]=(short)(4*t); cv0[n]=(short)(2*t);
      cu1[n]=(short)(4*t+2); cv1[n]=(short)(2*t+1); ++n;
    }
    for (int t = 0; t < 2; ++t) {                   // 2 DIAG duals
      dty[n]=2; cu0[n]=(short)(2*t); cu1[n]=(short)(2*t+1);
      cv0[n]=0; cv1[n]=0; ++n;
    }
    for (int t = 0; t < 4; ++t) {                   // 4 LIN duals
      dty[n]=3; cu0[n]=(short)(2*t); cu1[n]=(short)(2*t+1);
      cv0[n]=0; cv1[n]=0; ++n;
    }
    for (int t = 0; t < 2; ++t) {                   // 2 PAD duals
      dty[n]=4; cu0[n]=0; cu1[n]=0; cv0[n]=0; cv1[n]=0; ++n;
    }
    // slot table for prep: q -> (d,f); d=16 => linear theta=G[f]; 17 => pad
    for (int c = 0; c < 40; ++c) {
      int S = c / 4, a = c % 4;
      for (int kh = 0; kh < 2; ++kh)
        for (int e = 0; e < 2; ++e) {
          int q = S*16 + kh*8 + a*2 + e;
          int ty = dty[c];
          int u = kh ? cu1[c] : cu0[c];
          int v = kh ? cv1[c] : cv0[c];
          if (ty == 0 || ty == 1) { pd[q] = (short)u; pf[q] = (short)(2*v + e); }
          else if (ty == 2) { int s = u; pd[q] = pf[q] = (short)(4*s + 1 + 2*e); }
          else if (ty == 3) { pd[q] = 16; pf[q] = (short)(2*u + e); }
          else { pd[q] = 17; pf[q] = 0; }
        }
    }
  }
};
static constexpr PTab TAB{};

// ---------------- prep kernel: one block per component k ----------------
// Writes theta PRE-SWIZZLED into the ws image (exact LDS layout), fp16
// hi/lo split, so the density kernel stages with a conflict-free linear copy.
__global__ __launch_bounds__(256) void gm_prep_kernel(
    const float* __restrict__ m_w,
    const float* __restrict__ l_fac,
    const float* __restrict__ p_logits,
    char* __restrict__ thimg,           // IMG_BYTES swizzled theta image
    float* __restrict__ lc_out)
{
  const int k = blockIdx.x;
  const int tid = threadIdx.x;
  const int r = tid >> 4, c = tid & 15;
  __shared__ float A[D][D];
  __shared__ float L[D][D];
  __shared__ float S[2][D][D];
  __shared__ float Gd[D];
  __shared__ float ld[D];
  __shared__ float sm[K];
  const float LOG2E = 1.4426950408889634f;

  A[r][c] = l_fac[k * D * D + r * D + c];
  if (tid < K) sm[tid] = p_logits[tid];
  __syncthreads();

  {
    float s = 0.f;
    #pragma unroll
    for (int e = 0; e < D; ++e) s += A[r][e] * A[c][e];
    s *= (1.0f / D);
    L[r][c] = s;
    S[0][r][c] = s;
  }
  __syncthreads();

  if (tid < D) {
    float s = 0.f;
    #pragma unroll
    for (int f = 0; f < D; ++f) s += L[tid][f] * m_w[k * D + f];
    Gd[tid] = s;
  }

  int cb = 0;
  for (int j = 0; j < 15; ++j) {
    float pj = S[cb][j][j];
    float a = S[cb][r][j], b = S[cb][c][j], v = S[cb][r][c];
    if (tid == 0) ld[j] = logf(pj);
    if (r > j && c > j) S[cb ^ 1][r][c] = v - a * b / pj;
    cb ^= 1;
    __syncthreads();
  }
  if (tid == 0) {
    ld[15] = logf(S[cb][15][15]);
    float mx = -1e30f;
    for (int i = 0; i < K; ++i) mx = fmaxf(mx, sm[i]);
    float z = 0.f;
    for (int i = 0; i < K; ++i) z += expf(sm[i] - mx);
    float logp = sm[k] - mx - logf(z);
    float logdet_sqrt = 0.f;
    for (int j = 0; j < D; ++j) logdet_sqrt += ld[j];
    logdet_sqrt *= 0.5f;
    float cc = 0.f;
    for (int d2 = 0; d2 < D; ++d2) cc += m_w[k * D + d2] * Gd[d2];
    float lc = logp - 14.703016531274763f + logdet_sqrt - 0.5f * cc;
    lc_out[k] = LOG2E * lc;
  }
  __syncthreads();

  // theta -> fp16 hi/lo, stored at the swizzled image position
  for (int q = tid; q < R; q += 256) {
    int d = TAB.pd[q], f = TAB.pf[q];
    float th;
    if (d == 17) th = 0.f;
    else if (d == 16) th = LOG2E * Gd[f];
    else th = ((d == f) ? -0.5f : -1.0f) * LOG2E * L[d][f];
    _Float16 h = (_Float16)th;           // RNE
    _Float16 l = (_Float16)(th - (float)h);
    int m = q >> 3, e = q & 7;
    int sg = (k & 7) ^ (k >> 3);
    int phys = (m < 16) ? (m ^ sg) : (16 + ((m - 16) ^ (sg & 3)));
    size_t off = (size_t)k * LROW + (size_t)phys * 16 + (size_t)e * 2;
    *(unsigned short*)(thimg + off)         = __builtin_bit_cast(unsigned short, h);
    *(unsigned short*)(thimg + LHALF + off) = __builtin_bit_cast(unsigned short, l);
  }
}

__device__ __forceinline__ int bcst(f16x2 v) { return __builtin_bit_cast(int, v); }
__device__ __forceinline__ f16x2 fint(int v) { return __builtin_bit_cast(f16x2, v); }
// cvt_pkrtz returns __fp16x2; bit-cast to our _Float16-based f16x2
__device__ __forceinline__ f16x2 pkrtz(float a, float b) {
  return __builtin_bit_cast(f16x2, __builtin_amdgcn_cvt_pkrtz(a, b));
}

// build one dword of (phi_hh, phi_cross) for dual C; all indices constexpr
template<int C>
__device__ __forceinline__ void dualphi(int kh,
    const f16x2 (&xh)[8], const f16x2 (&xl)[8],
    const f16x2 (&sH)[16], const f16x2 (&sL)[16],
    const f16x2 (&dgh)[4], const f16x2 (&dgl)[4],
    int& hh, int& cx)
{
  constexpr int ty = TAB.dty[C];
  constexpr int U0 = TAB.cu0[C], V0 = TAB.cv0[C];
  constexpr int U1 = TAB.cu1[C], V1 = TAB.cv1[C];
  if constexpr (ty == 4) { hh = 0; cx = 0; }
  else if constexpr (ty == 3) {                 // linear: phi = x, zero VALU
    hh = kh ? bcst(xh[U1]) : bcst(xh[U0]);
    cx = kh ? bcst(xl[U1]) : bcst(xl[U0]);
  } else if constexpr (ty == 2) {               // odd diagonals: x_d^2
    f16x2 Dh = fint(kh ? bcst(dgh[U1]) : bcst(dgh[U0]));
    f16x2 Dl = fint(kh ? bcst(dgl[U1]) : bcst(dgl[U0]));
    f16x2 m = Dh * Dl;
    hh = bcst(Dh * Dh);
    cx = bcst(m + m);
  } else {                                      // ROW / ROWX: x_u * x_vpair
    f16x2 Uh = fint(kh ? bcst(sH[U1]) : bcst(sH[U0]));
    f16x2 Ul = fint(kh ? bcst(sL[U1]) : bcst(sL[U0]));
    f16x2 Vh, Vl;
    if constexpr (V0 == V1) { Vh = xh[V0]; Vl = xl[V0]; }
    else {
      Vh = fint(kh ? bcst(xh[V1]) : bcst(xh[V0]));
      Vl = fint(kh ? bcst(xl[V1]) : bcst(xl[V0]));
    }
    hh = bcst(Uh * Vh);
    cx = bcst(__builtin_elementwise_fma(Uh, Vl, Ul * Vh));
  }
}

template<int S>
__device__ __forceinline__ void do_step(int kh,
    const f16x2 (&xh)[8], const f16x2 (&xl)[8],
    const f16x2 (&sH)[16], const f16x2 (&sL)[16],
    const f16x2 (&dgh)[4], const f16x2 (&dgl)[4],
    const char* lthp, int base2, int sigh, f32x16& acc)
{
  int va;
  if constexpr (S < 8) va = base2 + ((S ^ sigh) << 5);
  else                 va = base2 + 256 + (((S - 8) ^ (sigh & 1)) << 5);
  int4v thv = *(const int4v*)(lthp + va);
  int4v tlv = *(const int4v*)(lthp + va + LHALF);
  int h0, h1, h2, h3, c0, c1, c2, c3;
  dualphi<S*4+0>(kh, xh, xl, sH, sL, dgh, dgl, h0, c0);
  dualphi<S*4+1>(kh, xh, xl, sH, sL, dgh, dgl, h1, c1);
  dualphi<S*4+2>(kh, xh, xl, sH, sL, dgh, dgl, h2, c2);
  dualphi<S*4+3>(kh, xh, xl, sH, sL, dgh, dgl, h3, c3);
  int4v hh = {h0, h1, h2, h3};
  int4v cx = {c0, c1, c2, c3};
  acc = __builtin_amdgcn_mfma_f32_32x32x16_f16(
      __builtin_bit_cast(f16x8, thv), __builtin_bit_cast(f16x8, hh), acc, 0, 0, 0);
  acc = __builtin_amdgcn_mfma_f32_32x32x16_f16(
      __builtin_bit_cast(f16x8, tlv), __builtin_bit_cast(f16x8, hh), acc, 0, 0, 0);
  acc = __builtin_amdgcn_mfma_f32_32x32x16_f16(
      __builtin_bit_cast(f16x8, thv), __builtin_bit_cast(f16x8, cx), acc, 0, 0, 0);
}

template<int... Ss>
__device__ __forceinline__ void all_steps(std::integer_sequence<int, Ss...>,
    int kh, const f16x2 (&xh)[8], const f16x2 (&xl)[8],
    const f16x2 (&sH)[16], const f16x2 (&sL)[16],
    const f16x2 (&dgh)[4], const f16x2 (&dgl)[4],
    const char* lthp, int base2, int sigh, f32x16& acc)
{
  (do_step<Ss>(kh, xh, xl, sH, sL, dgh, dgl, lthp, base2, sigh, acc), ...);
}

// ---------------- density kernel: fp16-pk phi, 1 tile per wave ----------------
__global__ __launch_bounds__(256) void gm_mfma_kernel(
    const float* __restrict__ x,
    const char*  __restrict__ thimg,
    const float* __restrict__ lc,
    float* __restrict__ out)
{
  __shared__ __align__(16) char lth[IMG_BYTES];
  const int tid = threadIdx.x;
  const int lane = tid & 63;
  const int p = lane & 31;
  const int kh = lane >> 5;
  const int t = blockIdx.x * 4 + (tid >> 6);

  // issue x loads first
  const float4* xp = (const float4*)(x + ((size_t)t * 32 + p) * D);
  float4 xv0 = xp[0], xv1 = xp[1], xv2 = xp[2], xv3 = xp[3];

  // stage theta image -> LDS, pure linear copy (conflict-free)
  for (int i = tid; i < IMG_BYTES / 16; i += 256) {
    int4v v = *(const int4v*)(thimg + i * 16);
    *(int4v*)(lth + i * 16) = v;
  }

  float lcv[16];
  #pragma unroll
  for (int i = 0; i < 16; ++i)
    lcv[i] = lc[(i & 3) + 8 * (i >> 2) + 4 * kh];

  __syncthreads();

  const int sig = (p & 7) ^ (p >> 3);
  const int base2 = p * LROW + ((kh ^ (sig & 1)) << 4);
  const int sigh = sig >> 1;

  float xs[16];
  xs[0]=xv0.x; xs[1]=xv0.y; xs[2]=xv0.z; xs[3]=xv0.w;
  xs[4]=xv1.x; xs[5]=xv1.y; xs[6]=xv1.z; xs[7]=xv1.w;
  xs[8]=xv2.x; xs[9]=xv2.y; xs[10]=xv2.z; xs[11]=xv2.w;
  xs[12]=xv3.x; xs[13]=xv3.y; xs[14]=xv3.z; xs[15]=xv3.w;

  // fp16 hi/lo split of x (RTZ; residual representable exactly)
  f16x2 xh[8], xl[8];
  #pragma unroll
  for (int i = 0; i < 8; ++i) {
    f16x2 h = pkrtz(xs[2*i], xs[2*i+1]);
    xh[i] = h;
    xl[i] = pkrtz(xs[2*i] - (float)h[0], xs[2*i+1] - (float)h[1]);
  }
  // row splats + odd-diagonal marshals
  f16x2 sH[16], sL[16], dgh[4], dgl[4];
  #pragma unroll
  for (int i = 0; i < 8; ++i) {
    sH[2*i]   = __builtin_shufflevector(xh[i], xh[i], 0, 0);
    sH[2*i+1] = __builtin_shufflevector(xh[i], xh[i], 1, 1);
    sL[2*i]   = __builtin_shufflevector(xl[i], xl[i], 0, 0);
    sL[2*i+1] = __builtin_shufflevector(xl[i], xl[i], 1, 1);
  }
  #pragma unroll
  for (int s = 0; s < 4; ++s) {
    dgh[s] = __builtin_shufflevector(xh[2*s], xh[2*s+1], 1, 3);
    dgl[s] = __builtin_shufflevector(xl[2*s], xl[2*s+1], 1, 3);
  }

  f32x16 acc;
  #pragma unroll
  for (int i = 0; i < 16; ++i) acc[i] = 0.f;

  all_steps(std::make_integer_sequence<int, NSTEPS>{}, kh, xh, xl,
            sH, sL, dgh, dgl, lth, base2, sigh, acc);

  float e[16];
  #pragma unroll
  for (int i = 0; i < 16; ++i)
    e[i] = __builtin_amdgcn_exp2f(acc[i] + lcv[i]);
  float a0 = (e[0] + e[1]) + (e[2] + e[3]);
  float a1 = (e[4] + e[5]) + (e[6] + e[7]);
  float a2 = (e[8] + e[9]) + (e[10] + e[11]);
  float a3 = (e[12] + e[13]) + (e[14] + e[15]);
  float ss = (a0 + a1) + (a2 + a3);
  ss += __shfl_xor(ss, 32);
  if (lane < 32) out[(size_t)t * 32 + p] = ss;
}

extern "C" void kernel_launch(void* const* d_in, const int* in_sizes, int n_in,
                              void* d_out, int out_size, void* d_ws, size_t ws_size,
                              hipStream_t stream) {
  const float* x        = (const float*)d_in[0];
  const float* m_w      = (const float*)d_in[1];
  const float* l_fac    = (const float*)d_in[2];
  const float* p_logits = (const float*)d_in[3];
  float* out = (float*)d_out;

  char* ws = (char*)d_ws;
  char*  thimg = ws;                          // IMG_BYTES swizzled theta image
  float* lcbuf = (float*)(ws + IMG_BYTES);    // K floats

  gm_prep_kernel<<<K, 256, 0, stream>>>(m_w, l_fac, p_logits, thimg, lcbuf);
  gm_mfma_kernel<<<NBLK, 256, 0, stream>>>(x, thimg, lcbuf, out);
}

// Round 13
// 21.345 us; speedup vs baseline: 3.8236x; 1.0105x over previous
//
#include <hip/hip_runtime.h>
#include <math.h>
#include <utility>

#define NPTS 262144
#define K 32
#define D 16
#define R 160            // 136 triangle + 16 linear + 8 pad -> 10 MFMA K-steps
#define NSTEPS 10
#define NBLK 1024        // 4 waves/block, 2 tiles/wave -> 8192 tiles
#define LROW 352         // 20 data granules + 2 pad granules per theta row
#define LHALF 11264      // 32 rows * 352 B ; thetaL image offset
#define IMG_BYTES 22528  // 2 * LHALF

typedef _Float16 f16x2 __attribute__((ext_vector_type(2)));
typedef _Float16 f16x8 __attribute__((ext_vector_type(8)));
typedef __attribute__((ext_vector_type(16))) float f32x16;
typedef __attribute__((ext_vector_type(4))) int int4v;

// ---- compile-time dual-cell table --------------------------------------
// 40 duals; dual c = (step S=c/4, dword a=c%4) holds 4 features: 2 for kh=0
// (slots S*16+a*2+{0,1}) and 2 for kh=1 (slots S*16+8+a*2+{0,1}).
// Types: 0=ROW (u-splat x v-pair, v shared between kh), 1=ROWX (even-diag
// leftovers, u and v differ), 2=DIAG (odd diagonals via marshaled pairs),
// 3=LIN (phi = x: register-ready, zero VALU), 4=PAD.
struct PTab {
  short dty[40], cu0[40], cv0[40], cu1[40], cv1[40];
  short pd[160], pf[160];              // per-slot (d,f) for the prep kernel
  constexpr PTab() : dty{}, cu0{}, cv0{}, cu1{}, cv1{}, pd{}, pf{} {
    int n = 0;
    for (int j = 0; j < 8; ++j)                     // 28 ROW duals
      for (int i = 0; i < j; ++i) {
        dty[n]=0; cu0[n]=(short)(2*i); cv0[n]=(short)j;
        cu1[n]=(short)(2*i+1); cv1[n]=(short)j; ++n;
      }
    for (int t = 0; t < 4; ++t) {                   // 4 ROWX duals
      dty[n]=1; cu0[n]=(short)(4*t); cv0[n]=(short)(2*t);
      cu1[n]=(short)(4*t+2); cv1[n]=(short)(2*t+1); ++n;
    }
    for (int t = 0; t < 2; ++t) {                   // 2 DIAG duals
      dty[n]=2; cu0[n]=(short)(2*t); cu1[n]=(short)(2*t+1);
      cv0[n]=0; cv1[n]=0; ++n;
    }
    for (int t = 0; t < 4; ++t) {                   // 4 LIN duals
      dty[n]=3; cu0[n]=(short)(2*t); cu1[n]=(short)(2*t+1);
      cv0[n]=0; cv1[n]=0; ++n;
    }
    for (int t = 0; t < 2; ++t) {                   // 2 PAD duals
      dty[n]=4; cu0[n]=0; cu1[n]=0; cv0[n]=0; cv1[n]=0; ++n;
    }
    // slot table for prep: q -> (d,f); d=16 => linear theta=G[f]; 17 => pad
    for (int c = 0; c < 40; ++c) {
      int S = c / 4, a = c % 4;
      for (int kh = 0; kh < 2; ++kh)
        for (int e = 0; e < 2; ++e) {
          int q = S*16 + kh*8 + a*2 + e;
          int ty = dty[c];
          int u = kh ? cu1[c] : cu0[c];
          int v = kh ? cv1[c] : cv0[c];
          if (ty == 0 || ty == 1) { pd[q] = (short)u; pf[q] = (short)(2*v + e); }
          else if (ty == 2) { int s = u; pd[q] = pf[q] = (short)(4*s + 1 + 2*e); }
          else if (ty == 3) { pd[q] = 16; pf[q] = (short)(2*u + e); }
          else { pd[q] = 17; pf[q] = 0; }
        }
    }
  }
};
static constexpr PTab TAB{};

// ---------------- prep kernel: one block per component k ----------------
// Writes theta PRE-SWIZZLED into the ws image (exact LDS layout), fp16
// hi/lo split, so the density kernel stages with a conflict-free linear copy.
__global__ __launch_bounds__(256) void gm_prep_kernel(
    const float* __restrict__ m_w,
    const float* __restrict__ l_fac,
    const float* __restrict__ p_logits,
    char* __restrict__ thimg,           // IMG_BYTES swizzled theta image
    float* __restrict__ lc_out)
{
  const int k = blockIdx.x;
  const int tid = threadIdx.x;
  const int r = tid >> 4, c = tid & 15;
  __shared__ float A[D][D];
  __shared__ float L[D][D];
  __shared__ float S[2][D][D];
  __shared__ float Gd[D];
  __shared__ float ld[D];
  __shared__ float sm[K];
  const float LOG2E = 1.4426950408889634f;

  A[r][c] = l_fac[k * D * D + r * D + c];
  if (tid < K) sm[tid] = p_logits[tid];
  __syncthreads();

  {
    float s = 0.f;
    #pragma unroll
    for (int e = 0; e < D; ++e) s += A[r][e] * A[c][e];
    s *= (1.0f / D);
    L[r][c] = s;
    S[0][r][c] = s;
  }
  __syncthreads();

  if (tid < D) {
    float s = 0.f;
    #pragma unroll
    for (int f = 0; f < D; ++f) s += L[tid][f] * m_w[k * D + f];
    Gd[tid] = s;
  }

  int cb = 0;
  for (int j = 0; j < 15; ++j) {
    float pj = S[cb][j][j];
    float a = S[cb][r][j], b = S[cb][c][j], v = S[cb][r][c];
    if (tid == 0) ld[j] = logf(pj);
    if (r > j && c > j) S[cb ^ 1][r][c] = v - a * b / pj;
    cb ^= 1;
    __syncthreads();
  }
  if (tid == 0) {
    ld[15] = logf(S[cb][15][15]);
    float mx = -1e30f;
    for (int i = 0; i < K; ++i) mx = fmaxf(mx, sm[i]);
    float z = 0.f;
    for (int i = 0; i < K; ++i) z += expf(sm[i] - mx);
    float logp = sm[k] - mx - logf(z);
    float logdet_sqrt = 0.f;
    for (int j = 0; j < D; ++j) logdet_sqrt += ld[j];
    logdet_sqrt *= 0.5f;
    float cc = 0.f;
    for (int d2 = 0; d2 < D; ++d2) cc += m_w[k * D + d2] * Gd[d2];
    float lc = logp - 14.703016531274763f + logdet_sqrt - 0.5f * cc;
    lc_out[k] = LOG2E * lc;
  }
  __syncthreads();

  // theta -> fp16 hi/lo, stored at the swizzled image position
  for (int q = tid; q < R; q += 256) {
    int d = TAB.pd[q], f = TAB.pf[q];
    float th;
    if (d == 17) th = 0.f;
    else if (d == 16) th = LOG2E * Gd[f];
    else th = ((d == f) ? -0.5f : -1.0f) * LOG2E * L[d][f];
    _Float16 h = (_Float16)th;           // RNE
    _Float16 l = (_Float16)(th - (float)h);
    int m = q >> 3, e = q & 7;
    int sg = (k & 7) ^ (k >> 3);
    int phys = (m < 16) ? (m ^ sg) : (16 + ((m - 16) ^ (sg & 3)));
    size_t off = (size_t)k * LROW + (size_t)phys * 16 + (size_t)e * 2;
    *(unsigned short*)(thimg + off)         = __builtin_bit_cast(unsigned short, h);
    *(unsigned short*)(thimg + LHALF + off) = __builtin_bit_cast(unsigned short, l);
  }
}

__device__ __forceinline__ int bcst(f16x2 v) { return __builtin_bit_cast(int, v); }
__device__ __forceinline__ f16x2 fint(int v) { return __builtin_bit_cast(f16x2, v); }
// cvt_pkrtz returns __fp16x2; bit-cast to our _Float16-based f16x2
__device__ __forceinline__ f16x2 pkrtz(float a, float b) {
  return __builtin_bit_cast(f16x2, __builtin_amdgcn_cvt_pkrtz(a, b));
}

// build one dword of (phi_hh, phi_cross) for dual C; all indices constexpr
template<int C>
__device__ __forceinline__ void dualphi(int kh,
    const f16x2 (&xh)[8], const f16x2 (&xl)[8],
    const f16x2 (&sH)[16], const f16x2 (&sL)[16],
    const f16x2 (&dgh)[4], const f16x2 (&dgl)[4],
    int& hh, int& cx)
{
  constexpr int ty = TAB.dty[C];
  constexpr int U0 = TAB.cu0[C], V0 = TAB.cv0[C];
  constexpr int U1 = TAB.cu1[C], V1 = TAB.cv1[C];
  if constexpr (ty == 4) { hh = 0; cx = 0; }
  else if constexpr (ty == 3) {                 // linear: phi = x, zero VALU
    hh = kh ? bcst(xh[U1]) : bcst(xh[U0]);
    cx = kh ? bcst(xl[U1]) : bcst(xl[U0]);
  } else if constexpr (ty == 2) {               // odd diagonals: x_d^2
    f16x2 Dh = fint(kh ? bcst(dgh[U1]) : bcst(dgh[U0]));
    f16x2 Dl = fint(kh ? bcst(dgl[U1]) : bcst(dgl[U0]));
    f16x2 m = Dh * Dl;
    hh = bcst(Dh * Dh);
    cx = bcst(m + m);
  } else {                                      // ROW / ROWX: x_u * x_vpair
    f16x2 Uh = fint(kh ? bcst(sH[U1]) : bcst(sH[U0]));
    f16x2 Ul = fint(kh ? bcst(sL[U1]) : bcst(sL[U0]));
    f16x2 Vh, Vl;
    if constexpr (V0 == V1) { Vh = xh[V0]; Vl = xl[V0]; }
    else {
      Vh = fint(kh ? bcst(xh[V1]) : bcst(xh[V0]));
      Vl = fint(kh ? bcst(xl[V1]) : bcst(xl[V0]));
    }
    hh = bcst(Uh * Vh);
    cx = bcst(__builtin_elementwise_fma(Uh, Vl, Ul * Vh));
  }
}

template<int S>
__device__ __forceinline__ void do_step(int kh,
    const f16x2 (&xh)[8], const f16x2 (&xl)[8],
    const f16x2 (&sH)[16], const f16x2 (&sL)[16],
    const f16x2 (&dgh)[4], const f16x2 (&dgl)[4],
    const char* lthp, int base2, int sigh, f32x16& acc)
{
  int va;
  if constexpr (S < 8) va = base2 + ((S ^ sigh) << 5);
  else                 va = base2 + 256 + (((S - 8) ^ (sigh & 1)) << 5);
  int4v thv = *(const int4v*)(lthp + va);
  int4v tlv = *(const int4v*)(lthp + va + LHALF);
  int h0, h1, h2, h3, c0, c1, c2, c3;
  dualphi<S*4+0>(kh, xh, xl, sH, sL, dgh, dgl, h0, c0);
  dualphi<S*4+1>(kh, xh, xl, sH, sL, dgh, dgl, h1, c1);
  dualphi<S*4+2>(kh, xh, xl, sH, sL, dgh, dgl, h2, c2);
  dualphi<S*4+3>(kh, xh, xl, sH, sL, dgh, dgl, h3, c3);
  int4v hh = {h0, h1, h2, h3};
  int4v cx = {c0, c1, c2, c3};
  acc = __builtin_amdgcn_mfma_f32_32x32x16_f16(
      __builtin_bit_cast(f16x8, thv), __builtin_bit_cast(f16x8, hh), acc, 0, 0, 0);
  acc = __builtin_amdgcn_mfma_f32_32x32x16_f16(
      __builtin_bit_cast(f16x8, tlv), __builtin_bit_cast(f16x8, hh), acc, 0, 0, 0);
  acc = __builtin_amdgcn_mfma_f32_32x32x16_f16(
      __builtin_bit_cast(f16x8, thv), __builtin_bit_cast(f16x8, cx), acc, 0, 0, 0);
}

template<int... Ss>
__device__ __forceinline__ void all_steps(std::integer_sequence<int, Ss...>,
    int kh, const f16x2 (&xh)[8], const f16x2 (&xl)[8],
    const f16x2 (&sH)[16], const f16x2 (&sL)[16],
    const f16x2 (&dgh)[4], const f16x2 (&dgl)[4],
    const char* lthp, int base2, int sigh, f32x16& acc)
{
  (do_step<Ss>(kh, xh, xl, sH, sL, dgh, dgl, lthp, base2, sigh, acc), ...);
}

// full per-tile pipeline from raw float4 x regs to the out store
__device__ __forceinline__ void process_tile(
    const float4 (&xv)[4], int t, int lane, int p, int kh,
    const char* lthp, int base2, int sigh, const float (&lcv)[16],
    float* __restrict__ out)
{
  float xs[16];
  xs[0]=xv[0].x; xs[1]=xv[0].y; xs[2]=xv[0].z; xs[3]=xv[0].w;
  xs[4]=xv[1].x; xs[5]=xv[1].y; xs[6]=xv[1].z; xs[7]=xv[1].w;
  xs[8]=xv[2].x; xs[9]=xv[2].y; xs[10]=xv[2].z; xs[11]=xv[2].w;
  xs[12]=xv[3].x; xs[13]=xv[3].y; xs[14]=xv[3].z; xs[15]=xv[3].w;

  // fp16 hi/lo split of x (RTZ; residual representable exactly)
  f16x2 xh[8], xl[8];
  #pragma unroll
  for (int i = 0; i < 8; ++i) {
    f16x2 h = pkrtz(xs[2*i], xs[2*i+1]);
    xh[i] = h;
    xl[i] = pkrtz(xs[2*i] - (float)h[0], xs[2*i+1] - (float)h[1]);
  }
  // row splats + odd-diagonal marshals
  f16x2 sH[16], sL[16], dgh[4], dgl[4];
  #pragma unroll
  for (int i = 0; i < 8; ++i) {
    sH[2*i]   = __builtin_shufflevector(xh[i], xh[i], 0, 0);
    sH[2*i+1] = __builtin_shufflevector(xh[i], xh[i], 1, 1);
    sL[2*i]   = __builtin_shufflevector(xl[i], xl[i], 0, 0);
    sL[2*i+1] = __builtin_shufflevector(xl[i], xl[i], 1, 1);
  }
  #pragma unroll
  for (int s = 0; s < 4; ++s) {
    dgh[s] = __builtin_shufflevector(xh[2*s], xh[2*s+1], 1, 3);
    dgl[s] = __builtin_shufflevector(xl[2*s], xl[2*s+1], 1, 3);
  }

  f32x16 acc;
  #pragma unroll
  for (int i = 0; i < 16; ++i) acc[i] = 0.f;

  all_steps(std::make_integer_sequence<int, NSTEPS>{}, kh, xh, xl,
            sH, sL, dgh, dgl, lthp, base2, sigh, acc);

  float e[16];
  #pragma unroll
  for (int i = 0; i < 16; ++i)
    e[i] = __builtin_amdgcn_exp2f(acc[i] + lcv[i]);
  float a0 = (e[0] + e[1]) + (e[2] + e[3]);
  float a1 = (e[4] + e[5]) + (e[6] + e[7]);
  float a2 = (e[8] + e[9]) + (e[10] + e[11]);
  float a3 = (e[12] + e[13]) + (e[14] + e[15]);
  float ss = (a0 + a1) + (a2 + a3);
  ss += __shfl_xor(ss, 32);
  if (lane < 32) out[(size_t)t * 32 + p] = ss;
}

// ---------------- density kernel: 2 tiles/wave, both x prefetched ----------------
// Round-12 decomposition: per-wave fixed cost F (x-load stall + staging +
// barrier + drain) ~2x the per-tile compute C. Amortize: both tiles' x
// issued up-front (latency hides under staging+barrier), tile 2 computes
// back-to-back with no memory phase. Staging traffic halves.
__global__ __launch_bounds__(256) void gm_mfma_kernel(
    const float* __restrict__ x,
    const char*  __restrict__ thimg,
    const float* __restrict__ lc,
    float* __restrict__ out)
{
  __shared__ __align__(16) char lth[IMG_BYTES];
  const int tid = threadIdx.x;
  const int lane = tid & 63;
  const int p = lane & 31;
  const int kh = lane >> 5;
  const int t0 = (blockIdx.x * 4 + (tid >> 6)) * 2;   // 2 tiles per wave

  // issue BOTH tiles' x loads first (8 dwordx4 in flight across staging)
  const float4* xp0 = (const float4*)(x + ((size_t)t0 * 32 + p) * D);
  const float4* xp1 = (const float4*)(x + ((size_t)(t0 + 1) * 32 + p) * D);
  float4 xva[4], xvb[4];
  #pragma unroll
  for (int i = 0; i < 4; ++i) { xva[i] = xp0[i]; xvb[i] = xp1[i]; }

  // stage theta image -> LDS, pure linear copy (conflict-free)
  for (int i = tid; i < IMG_BYTES / 16; i += 256) {
    int4v v = *(const int4v*)(thimg + i * 16);
    *(int4v*)(lth + i * 16) = v;
  }

  float lcv[16];
  #pragma unroll
  for (int i = 0; i < 16; ++i)
    lcv[i] = lc[(i & 3) + 8 * (i >> 2) + 4 * kh];

  __syncthreads();

  const int sig = (p & 7) ^ (p >> 3);
  const int base2 = p * LROW + ((kh ^ (sig & 1)) << 4);
  const int sigh = sig >> 1;

  process_tile(xva, t0,     lane, p, kh, lth, base2, sigh, lcv, out);
  process_tile(xvb, t0 + 1, lane, p, kh, lth, base2, sigh, lcv, out);
}

extern "C" void kernel_launch(void* const* d_in, const int* in_sizes, int n_in,
                              void* d_out, int out_size, void* d_ws, size_t ws_size,
                              hipStream_t stream) {
  const float* x        = (const float*)d_in[0];
  const float* m_w      = (const float*)d_in[1];
  const float* l_fac    = (const float*)d_in[2];
  const float* p_logits = (const float*)d_in[3];
  float* out = (float*)d_out;

  char* ws = (char*)d_ws;
  char*  thimg = ws;                          // IMG_BYTES swizzled theta image
  float* lcbuf = (float*)(ws + IMG_BYTES);    // K floats

  gm_prep_kernel<<<K, 256, 0, stream>>>(m_w, l_fac, p_logits, thimg, lcbuf);
  gm_mfma_kernel<<<NBLK, 256, 0, stream>>>(x, thimg, lcbuf, out);
}